// Round 1
// baseline (884.002 us; speedup 1.0000x reference)
//
#include <hip/hip_runtime.h>
#include <hip/hip_bf16.h>

#define Bq 4
#define Nn 4
#define Cc 256
#define Hh 100
#define Ww 152
#define HW (Hh * Ww)          // 15200
#define P4 (HW / 4)           // 3800
#define NMAP (Bq * (1 + Nn))  // 20
#define TILE 32
#define TPB (HW / TILE)       // 475 tiles per image

// ---------------------------------------------------------------------------
// K1: per-pixel channel sums (fp64 accumulate) for features + nearby maps.
// map m = b*5 + r ; r==0 -> features[b], r=1..4 -> nearby[b][r-1]
// ---------------------------------------------------------------------------
__global__ __launch_bounds__(256) void k_sums(const float* __restrict__ feat,
                                              const float* __restrict__ nearf,
                                              double* __restrict__ s_all) {
    int t = blockIdx.x * blockDim.x + threadIdx.x;
    if (t >= NMAP * P4) return;
    int m = t / P4, p4 = t % P4;
    int b = m / 5, r = m % 5;
    const float* src = (r == 0)
        ? (feat + (size_t)b * Cc * HW)
        : (nearf + ((size_t)(b * Nn + (r - 1))) * Cc * HW);
    src += (size_t)p4 * 4;
    double a0 = 0, a1 = 0, a2 = 0, a3 = 0;
#pragma unroll 8
    for (int c = 0; c < Cc; ++c) {
        float4 v = *(const float4*)(src + (size_t)c * HW);
        a0 += (double)v.x; a1 += (double)v.y; a2 += (double)v.z; a3 += (double)v.w;
    }
    double* dst = s_all + (size_t)m * HW + (size_t)p4 * 4;
    dst[0] = a0; dst[1] = a1; dst[2] = a2; dst[3] = a3;
}

// ---------------------------------------------------------------------------
// K2: census-hash similarity + softmax over N -> weights wt[b][n][p]
// ---------------------------------------------------------------------------
__global__ __launch_bounds__(256) void k_sim(const float* __restrict__ feat,
                                             const float* __restrict__ nearf,
                                             const double* __restrict__ s_all,
                                             float* __restrict__ wt) {
    int t = blockIdx.x * blockDim.x + threadIdx.x;
    if (t >= Bq * HW) return;
    int b = t / HW, p = t % HW;
    int i = p / Ww, j = p % Ww;
    int im = (i > 0) ? i - 1 : 0;
    int ip = (i < Hh - 1) ? i + 1 : Hh - 1;
    int jm = (j > 0) ? j - 1 : 0;
    int jp = (j < Ww - 1) ? j + 1 : Ww - 1;
    int off[9];
    off[0] = im * Ww + jm; off[1] = im * Ww + j; off[2] = im * Ww + jp;
    off[3] = i  * Ww + jm; off[4] = i  * Ww + j; off[5] = i  * Ww + jp;
    off[6] = ip * Ww + jm; off[7] = ip * Ww + j; off[8] = ip * Ww + jp;

    const double inv = 1.0 / (9.0 * (double)Cc);
    const double* sb = s_all + (size_t)b * 5 * HW;
    double av[5];
#pragma unroll
    for (int r = 0; r < 5; ++r) {
        const double* s = sb + (size_t)r * HW;
        double a = 0.0;
#pragma unroll
        for (int k = 0; k < 9; ++k) a += s[off[k]];
        av[r] = a * inv;
    }

    const float* fb = feat + (size_t)b * Cc * HW;
    const float* nb = nearf + (size_t)b * Nn * Cc * HW;
    int cnt0 = 0, cnt1 = 0, cnt2 = 0, cnt3 = 0;
    for (int c = 0; c < Cc; ++c) {
        const float* fc = fb + (size_t)c * HW;
        unsigned mf = 0;
#pragma unroll
        for (int k = 0; k < 9; ++k)
            mf |= (unsigned)((double)fc[off[k]] >= av[0]) << k;
        const float* nc0 = nb + (size_t)c * HW;
        unsigned mn;
        mn = 0;
#pragma unroll
        for (int k = 0; k < 9; ++k)
            mn |= (unsigned)((double)nc0[off[k]] >= av[1]) << k;
        cnt0 += 9 - __popc(mf ^ mn);
        const float* nc1 = nc0 + (size_t)Cc * HW;
        mn = 0;
#pragma unroll
        for (int k = 0; k < 9; ++k)
            mn |= (unsigned)((double)nc1[off[k]] >= av[2]) << k;
        cnt1 += 9 - __popc(mf ^ mn);
        const float* nc2 = nc1 + (size_t)Cc * HW;
        mn = 0;
#pragma unroll
        for (int k = 0; k < 9; ++k)
            mn |= (unsigned)((double)nc2[off[k]] >= av[3]) << k;
        cnt2 += 9 - __popc(mf ^ mn);
        const float* nc3 = nc2 + (size_t)Cc * HW;
        mn = 0;
#pragma unroll
        for (int k = 0; k < 9; ++k)
            mn |= (unsigned)((double)nc3[off[k]] >= av[4]) << k;
        cnt3 += 9 - __popc(mf ^ mn);
    }

    float c0 = (float)cnt0, c1 = (float)cnt1, c2 = (float)cnt2, c3 = (float)cnt3;
    float mx = fmaxf(fmaxf(c0, c1), fmaxf(c2, c3));
    float e0 = expf(c0 - mx), e1 = expf(c1 - mx), e2 = expf(c2 - mx), e3 = expf(c3 - mx);
    float rs = 1.0f / (e0 + e1 + e2 + e3);
    float* wb = wt + (size_t)b * Nn * HW + p;
    wb[0 * HW] = e0 * rs;
    wb[1 * HW] = e1 * rs;
    wb[2 * HW] = e2 * rs;
    wb[3 * HW] = e3 * rs;
}

// ---------------------------------------------------------------------------
// K3: fused = features + sum_n wt_n * nearby_n ; out = w_fuse @ fused + b_fuse
// One block per (b, 32-pixel tile). Phase A stages fused[256][32] in LDS,
// phase B: thread t owns output channel o=t, 32 fp32 accumulators.
// ---------------------------------------------------------------------------
__global__ __launch_bounds__(256) void k_fuse(const float* __restrict__ feat,
                                              const float* __restrict__ nearf,
                                              const float* __restrict__ wt,
                                              const float* __restrict__ wf,
                                              const float* __restrict__ bf,
                                              float* __restrict__ out) {
    __shared__ float fl[Cc * TILE];  // 32 KB
    int blk = blockIdx.x;            // 0 .. Bq*TPB-1
    int b = blk / TPB;
    int tp = blk % TPB;
    int p0 = tp * TILE;
    int t = threadIdx.x;

    // ---- Phase A: build fused tile ----
    {
        int p = t % TILE;           // 0..31
        int cg = t / TILE;          // 0..7
        int pp = p0 + p;
        float w0 = wt[((size_t)b * Nn + 0) * HW + pp];
        float w1 = wt[((size_t)b * Nn + 1) * HW + pp];
        float w2 = wt[((size_t)b * Nn + 2) * HW + pp];
        float w3 = wt[((size_t)b * Nn + 3) * HW + pp];
        const float* fb = feat + (size_t)b * Cc * HW + pp;
        const float* nb = nearf + (size_t)b * Nn * Cc * HW + pp;
#pragma unroll 4
        for (int k = 0; k < Cc / 8; ++k) {
            int c = cg * (Cc / 8) + k;
            float v = fb[(size_t)c * HW];
            v += w0 * nb[((size_t)0 * Cc + c) * HW];
            v += w1 * nb[((size_t)1 * Cc + c) * HW];
            v += w2 * nb[((size_t)2 * Cc + c) * HW];
            v += w3 * nb[((size_t)3 * Cc + c) * HW];
            fl[c * TILE + p] = v;
        }
    }
    __syncthreads();

    // ---- Phase B: 256x256 x (256xTILE) GEMM, o = t ----
    {
        int o = t;
        float bias = bf[o];
        float4 acc[TILE / 4];
#pragma unroll
        for (int q = 0; q < TILE / 4; ++q)
            acc[q] = make_float4(bias, bias, bias, bias);
        const float* wrow = wf + (size_t)o * Cc;
        for (int c = 0; c < Cc; c += 4) {
            float4 w4 = *(const float4*)(wrow + c);
#pragma unroll
            for (int s = 0; s < 4; ++s) {
                float ws = (s == 0) ? w4.x : (s == 1) ? w4.y : (s == 2) ? w4.z : w4.w;
                const float4* row = (const float4*)(fl + (c + s) * TILE);
#pragma unroll
                for (int q = 0; q < TILE / 4; ++q) {
                    float4 f4 = row[q];
                    acc[q].x += ws * f4.x;
                    acc[q].y += ws * f4.y;
                    acc[q].z += ws * f4.z;
                    acc[q].w += ws * f4.w;
                }
            }
        }
        float* ob = out + ((size_t)b * Cc + o) * HW + p0;
#pragma unroll
        for (int q = 0; q < TILE / 4; ++q)
            *(float4*)(ob + q * 4) = acc[q];
    }
}

extern "C" void kernel_launch(void* const* d_in, const int* in_sizes, int n_in,
                              void* d_out, int out_size, void* d_ws, size_t ws_size,
                              hipStream_t stream) {
    const float* feat = (const float*)d_in[0];   // [B,C,H,W]
    const float* nearf = (const float*)d_in[1];  // [B,N,C,H,W]
    const float* wf = (const float*)d_in[2];     // [C,C]
    const float* bf = (const float*)d_in[3];     // [C]
    float* out = (float*)d_out;                  // [B,C,H,W]

    double* s_all = (double*)d_ws;                        // 20*HW doubles = 2.43 MB
    float* wt = (float*)((char*)d_ws + (size_t)NMAP * HW * sizeof(double));  // B*N*HW floats

    {
        int threads = NMAP * P4;  // 76000
        int blocks = (threads + 255) / 256;
        k_sums<<<blocks, 256, 0, stream>>>(feat, nearf, s_all);
    }
    {
        int threads = Bq * HW;  // 60800
        int blocks = (threads + 255) / 256;
        k_sim<<<blocks, 256, 0, stream>>>(feat, nearf, s_all, wt);
    }
    {
        int blocks = Bq * TPB;  // 1900
        k_fuse<<<blocks, 256, 0, stream>>>(feat, nearf, wt, wf, bf, out);
    }
}

// Round 2
// 770.602 us; speedup vs baseline: 1.1472x; 1.1472x over previous
//
#include <hip/hip_runtime.h>
#include <math.h>

#define Bq 4
#define Nn 4
#define Cc 256
#define Hh 100
#define Ww 152
#define HW (Hh * Ww)          // 15200
#define NMAP (Bq * 5)         // 20 maps: per b: [feat, n0..n3]
#define TILE 32
#define TPB (HW / TILE)       // 475 (15200 % 32 == 0)
#define CSPLIT 8
#define CCHUNK (Cc / CSPLIT)  // 32

// ws layout (bytes):
//   s_all : double[NMAP*HW]          @ 0          (2,432,000)
//   thr   : float [NMAP*HW]          @ 2,432,000  (1,216,000)
//   pcnt  : u64   [CSPLIT*Bq*HW]     @ 3,648,000  (3,891,200)
//   wt    : float [Bq*Nn*HW]         @ 7,539,200  (  972,800)
//   wT    : float [Cc*Cc]            @ 8,512,000  (  262,144)
#define OFF_SALL 0
#define OFF_THR  2432000
#define OFF_PCNT 3648000
#define OFF_WT   7539200
#define OFF_WTR  8512000

// ---------------------------------------------------------------------------
// K0: transpose w_fuse [o][c] -> wT [c][o] (one-time, 256KB)
// ---------------------------------------------------------------------------
__global__ __launch_bounds__(256) void k_wtr(const float* __restrict__ wf,
                                             float* __restrict__ wT) {
    int t = blockIdx.x * blockDim.x + threadIdx.x;
    if (t >= Cc * Cc) return;
    int c = t / Cc, o = t % Cc;           // consecutive lanes -> consecutive o (coalesced write)
    wT[c * Cc + o] = wf[o * Cc + c];
}

// ---------------------------------------------------------------------------
// K1: per-(map,pixel) channel sum in fp64. One thread per (m,p): 304k threads.
// ---------------------------------------------------------------------------
__global__ __launch_bounds__(256) void k_sums(const float* __restrict__ feat,
                                              const float* __restrict__ nearf,
                                              double* __restrict__ s_all) {
    int t = blockIdx.x * blockDim.x + threadIdx.x;
    if (t >= NMAP * HW) return;
    int m = t / HW, p = t % HW;
    int b = m / 5, r = m % 5;
    const float* src = (r == 0)
        ? (feat + (size_t)b * Cc * HW)
        : (nearf + ((size_t)(b * Nn + (r - 1))) * Cc * HW);
    src += p;
    double a0 = 0, a1 = 0, a2 = 0, a3 = 0;
#pragma unroll 8
    for (int c = 0; c < Cc; c += 4) {
        a0 += (double)src[(size_t)(c + 0) * HW];
        a1 += (double)src[(size_t)(c + 1) * HW];
        a2 += (double)src[(size_t)(c + 2) * HW];
        a3 += (double)src[(size_t)(c + 3) * HW];
    }
    s_all[(size_t)m * HW + p] = (a0 + a1) + (a2 + a3);
}

// ---------------------------------------------------------------------------
// K2: box-9 of channel sums -> fp64 avg -> exact float threshold.
// thr = smallest float >= avg  =>  (v >= thr) in fp32 == ((double)v >= avg).
// ---------------------------------------------------------------------------
__global__ __launch_bounds__(256) void k_thr(const double* __restrict__ s_all,
                                             float* __restrict__ thr) {
    int t = blockIdx.x * blockDim.x + threadIdx.x;
    if (t >= NMAP * HW) return;
    int m = t / HW, p = t % HW;
    int i = p / Ww, j = p % Ww;
    int im = (i > 0) ? i - 1 : 0;
    int ip = (i < Hh - 1) ? i + 1 : Hh - 1;
    int jm = (j > 0) ? j - 1 : 0;
    int jp = (j < Ww - 1) ? j + 1 : Ww - 1;
    const double* s = s_all + (size_t)m * HW;
    double a = s[im * Ww + jm] + s[im * Ww + j] + s[im * Ww + jp]
             + s[i  * Ww + jm] + s[i  * Ww + j] + s[i  * Ww + jp]
             + s[ip * Ww + jm] + s[ip * Ww + j] + s[ip * Ww + jp];
    a *= (1.0 / (9.0 * (double)Cc));
    float f = (float)a;
    if ((double)f < a) f = nextafterf(f, HUGE_VALF);
    thr[(size_t)m * HW + p] = f;
}

// ---------------------------------------------------------------------------
// K3: census partial counts. blockIdx.y = channel split (32 ch each).
// Pure fp32 compares against exact thresholds. Output: packed 4xu16 per
// (split, b, p). Partial counts <= 32*9 = 288, total <= 2304 -> no carry.
// ---------------------------------------------------------------------------
__global__ __launch_bounds__(256) void k_census(const float* __restrict__ feat,
                                                const float* __restrict__ nearf,
                                                const float* __restrict__ thr,
                                                unsigned long long* __restrict__ pcnt) {
    int t = blockIdx.x * blockDim.x + threadIdx.x;
    if (t >= Bq * HW) return;
    int s = blockIdx.y;
    int b = t / HW, p = t % HW;
    int i = p / Ww, j = p % Ww;
    int im = (i > 0) ? i - 1 : 0;
    int ip = (i < Hh - 1) ? i + 1 : Hh - 1;
    int jm = (j > 0) ? j - 1 : 0;
    int jp = (j < Ww - 1) ? j + 1 : Ww - 1;
    int off[9];
    off[0] = im * Ww + jm; off[1] = im * Ww + j; off[2] = im * Ww + jp;
    off[3] = i  * Ww + jm; off[4] = i  * Ww + j; off[5] = i  * Ww + jp;
    off[6] = ip * Ww + jm; off[7] = ip * Ww + j; off[8] = ip * Ww + jp;

    float tf = thr[(size_t)(b * 5 + 0) * HW + p];
    float t0 = thr[(size_t)(b * 5 + 1) * HW + p];
    float t1 = thr[(size_t)(b * 5 + 2) * HW + p];
    float t2 = thr[(size_t)(b * 5 + 3) * HW + p];
    float t3 = thr[(size_t)(b * 5 + 4) * HW + p];

    const float* fb = feat + ((size_t)b * Cc + s * CCHUNK) * HW;
    const float* nb = nearf + ((size_t)(b * Nn) * Cc + s * CCHUNK) * HW;

    int cnt0 = 0, cnt1 = 0, cnt2 = 0, cnt3 = 0;
#pragma unroll 2
    for (int ci = 0; ci < CCHUNK; ++ci) {
        const float* fc = fb + (size_t)ci * HW;
        unsigned mf = 0;
#pragma unroll
        for (int k = 0; k < 9; ++k) mf |= (unsigned)(fc[off[k]] >= tf) << k;
        const float* nc0 = nb + (size_t)ci * HW;
        unsigned mn = 0;
#pragma unroll
        for (int k = 0; k < 9; ++k) mn |= (unsigned)(nc0[off[k]] >= t0) << k;
        cnt0 += 9 - __popc(mf ^ mn);
        const float* nc1 = nc0 + (size_t)Cc * HW;
        mn = 0;
#pragma unroll
        for (int k = 0; k < 9; ++k) mn |= (unsigned)(nc1[off[k]] >= t1) << k;
        cnt1 += 9 - __popc(mf ^ mn);
        const float* nc2 = nc1 + (size_t)Cc * HW;
        mn = 0;
#pragma unroll
        for (int k = 0; k < 9; ++k) mn |= (unsigned)(nc2[off[k]] >= t2) << k;
        cnt2 += 9 - __popc(mf ^ mn);
        const float* nc3 = nc2 + (size_t)Cc * HW;
        mn = 0;
#pragma unroll
        for (int k = 0; k < 9; ++k) mn |= (unsigned)(nc3[off[k]] >= t3) << k;
        cnt3 += 9 - __popc(mf ^ mn);
    }
    unsigned long long packed = (unsigned long long)(unsigned)cnt0
                              | ((unsigned long long)(unsigned)cnt1 << 16)
                              | ((unsigned long long)(unsigned)cnt2 << 32)
                              | ((unsigned long long)(unsigned)cnt3 << 48);
    pcnt[(size_t)s * (Bq * HW) + t] = packed;
}

// ---------------------------------------------------------------------------
// K4: reduce 8 packed partials -> softmax over N -> weights wt[b][n][p]
// ---------------------------------------------------------------------------
__global__ __launch_bounds__(256) void k_soft(const unsigned long long* __restrict__ pcnt,
                                              float* __restrict__ wt) {
    int t = blockIdx.x * blockDim.x + threadIdx.x;
    if (t >= Bq * HW) return;
    unsigned long long a = 0;
#pragma unroll
    for (int s = 0; s < CSPLIT; ++s) a += pcnt[(size_t)s * (Bq * HW) + t];
    float c0 = (float)(int)(a & 0xFFFF);
    float c1 = (float)(int)((a >> 16) & 0xFFFF);
    float c2 = (float)(int)((a >> 32) & 0xFFFF);
    float c3 = (float)(int)((a >> 48) & 0xFFFF);
    float mx = fmaxf(fmaxf(c0, c1), fmaxf(c2, c3));
    float e0 = expf(c0 - mx), e1 = expf(c1 - mx), e2 = expf(c2 - mx), e3 = expf(c3 - mx);
    float rs = 1.0f / (e0 + e1 + e2 + e3);
    int b = t / HW, p = t % HW;
    float* wb = wt + (size_t)b * Nn * HW + p;
    wb[0 * (size_t)HW] = e0 * rs;
    wb[1 * (size_t)HW] = e1 * rs;
    wb[2 * (size_t)HW] = e2 * rs;
    wb[3 * (size_t)HW] = e3 * rs;
}

// ---------------------------------------------------------------------------
// K5: fused = feat + sum_n wt_n*near_n (LDS tile), then out = wT^T @ fused + b.
// Phase B: thread = (og = t&63, pg = t>>6); 4 output ch x 8 px per thread;
// 32 FMA per {1 coalesced float4 wT load + 2 broadcast ds_read_b128}.
// ---------------------------------------------------------------------------
__global__ __launch_bounds__(256) void k_fuse(const float* __restrict__ feat,
                                              const float* __restrict__ nearf,
                                              const float* __restrict__ wt,
                                              const float* __restrict__ wT,
                                              const float* __restrict__ bf,
                                              float* __restrict__ out) {
    __shared__ float fl[Cc * TILE];  // 32 KB, fl[c][px]
    int blk = blockIdx.x;
    int b = blk / TPB;
    int tp = blk % TPB;
    int p0 = tp * TILE;
    int t = threadIdx.x;

    // ---- Phase A: build fused tile ----
    {
        int px = t & (TILE - 1);    // 0..31
        int cg = t >> 5;            // 0..7, 32 channels each
        int pp = p0 + px;
        float w0 = wt[((size_t)b * Nn + 0) * HW + pp];
        float w1 = wt[((size_t)b * Nn + 1) * HW + pp];
        float w2 = wt[((size_t)b * Nn + 2) * HW + pp];
        float w3 = wt[((size_t)b * Nn + 3) * HW + pp];
        const float* fb = feat + (size_t)b * Cc * HW + pp;
        const float* nb = nearf + (size_t)b * Nn * Cc * HW + pp;
#pragma unroll 4
        for (int k = 0; k < Cc / 8; ++k) {
            int c = cg * (Cc / 8) + k;
            float v = fb[(size_t)c * HW];
            v += w0 * nb[((size_t)0 * Cc + c) * HW];
            v += w1 * nb[((size_t)1 * Cc + c) * HW];
            v += w2 * nb[((size_t)2 * Cc + c) * HW];
            v += w3 * nb[((size_t)3 * Cc + c) * HW];
            fl[c * TILE + px] = v;
        }
    }
    __syncthreads();

    // ---- Phase B ----
    {
        int og = t & 63;            // output channel group: o = og*4 + i
        int pg = t >> 6;            // pixel group: px = pg*8 .. pg*8+7
        const float4* wT4 = (const float4*)wT;    // [Cc][Cc/4]
        const float4* flv = (const float4*)fl;    // [Cc][TILE/4]
        float4 acc[4][2];
#pragma unroll
        for (int i = 0; i < 4; ++i) {
            float bi = bf[og * 4 + i];
            acc[i][0] = make_float4(bi, bi, bi, bi);
            acc[i][1] = make_float4(bi, bi, bi, bi);
        }
#pragma unroll 4
        for (int c = 0; c < Cc; ++c) {
            float4 wv = wT4[c * (Cc / 4) + og];
            float4 f0 = flv[c * (TILE / 4) + pg * 2];
            float4 f1 = flv[c * (TILE / 4) + pg * 2 + 1];
#pragma unroll
            for (int i = 0; i < 4; ++i) {
                float wi = (i == 0) ? wv.x : (i == 1) ? wv.y : (i == 2) ? wv.z : wv.w;
                acc[i][0].x += wi * f0.x; acc[i][0].y += wi * f0.y;
                acc[i][0].z += wi * f0.z; acc[i][0].w += wi * f0.w;
                acc[i][1].x += wi * f1.x; acc[i][1].y += wi * f1.y;
                acc[i][1].z += wi * f1.z; acc[i][1].w += wi * f1.w;
            }
        }
#pragma unroll
        for (int i = 0; i < 4; ++i) {
            float* ob = out + ((size_t)b * Cc + og * 4 + i) * HW + p0 + pg * 8;
            *(float4*)(ob + 0) = acc[i][0];
            *(float4*)(ob + 4) = acc[i][1];
        }
    }
}

extern "C" void kernel_launch(void* const* d_in, const int* in_sizes, int n_in,
                              void* d_out, int out_size, void* d_ws, size_t ws_size,
                              hipStream_t stream) {
    const float* feat = (const float*)d_in[0];   // [B,C,H,W]
    const float* nearf = (const float*)d_in[1];  // [B,N,C,H,W]
    const float* wf = (const float*)d_in[2];     // [C,C]
    const float* bf = (const float*)d_in[3];     // [C]
    float* out = (float*)d_out;                  // [B,C,H,W]

    char* ws = (char*)d_ws;
    double* s_all = (double*)(ws + OFF_SALL);
    float* thr = (float*)(ws + OFF_THR);
    unsigned long long* pcnt = (unsigned long long*)(ws + OFF_PCNT);
    float* wt = (float*)(ws + OFF_WT);
    float* wT = (float*)(ws + OFF_WTR);

    k_wtr<<<(Cc * Cc + 255) / 256, 256, 0, stream>>>(wf, wT);
    k_sums<<<(NMAP * HW + 255) / 256, 256, 0, stream>>>(feat, nearf, s_all);
    k_thr<<<(NMAP * HW + 255) / 256, 256, 0, stream>>>(s_all, thr);
    {
        dim3 grid((Bq * HW + 255) / 256, CSPLIT);
        k_census<<<grid, 256, 0, stream>>>(feat, nearf, thr, pcnt);
    }
    k_soft<<<(Bq * HW + 255) / 256, 256, 0, stream>>>(pcnt, wt);
    k_fuse<<<Bq * TPB, 256, 0, stream>>>(feat, nearf, wt, wT, bf, out);
}